// Round 2
// baseline (170.671 us; speedup 1.0000x reference)
//
#include <hip/hip_runtime.h>
#include <math.h>

#define N_NODES 20000
#define N_EDGES 320000
#define C_IN  256
#define C_HID 256
#define C_OUT 128
#define NEG_SLOPE 0.2f
#define CAP   256   // padded-CSR slots per node (real edges only; self-loop implicit)
#define GEMM1_BLKS (N_NODES / 32)          // 625
#define SCAT_BLKS  ((N_EDGES + 255) / 256) // 1250
#define AGG_PAD 280 // 256 + 24: LDS row stride (560 B = 16B-aligned, 8 bank-start groups)

typedef __attribute__((ext_vector_type(8))) short bf16x8;
typedef __attribute__((ext_vector_type(4))) float f32x4;

// ---- all scratch in module globals (ws_size unknown; globals are safe) ----
__device__ __align__(16) unsigned short c_W1h[C_IN * C_HID], c_W1l[C_IN * C_HID];
__device__ __align__(16) unsigned short c_W2h[C_HID * C_OUT], c_W2l[C_HID * C_OUT];
__device__ float c_as1f[C_HID], c_ad1f[C_HID], c_b1f[C_HID];
__device__ float c_as2f[C_OUT], c_ad2f[C_OUT], c_b2f[C_OUT];
__device__ __align__(16) unsigned short g_h1b[(size_t)N_NODES * C_HID]; // h1 bf16
__device__ __align__(16) unsigned short g_h2b[(size_t)N_NODES * C_OUT]; // h2 bf16
__device__ float g_alps1[N_NODES], g_alpd1[N_NODES];
__device__ float g_alps2[N_NODES], g_alpd2[N_NODES];
__device__ int   g_cursor[N_NODES];            // per-node real-edge count
__device__ int   g_srcidx[(size_t)N_NODES * CAP];
__device__ int   g_is64;    // edge_index arrived as raw int64 words
__device__ int   g_isf32;   // float inputs arrived as raw fp32 words

__device__ __forceinline__ float bf2f(unsigned short b){
  unsigned int u = ((unsigned int)b) << 16;
  return __builtin_bit_cast(float, u);
}
__device__ __forceinline__ unsigned short f2bf(float f){
  unsigned int u = __builtin_bit_cast(unsigned int, f);
  u += 0x7fffu + ((u >> 16) & 1u);   // round-to-nearest-even
  return (unsigned short)(u >> 16);
}
__device__ __forceinline__ int clampi(int v){
  v = v < 0 ? 0 : v;
  return v >= N_NODES ? N_NODES - 1 : v;
}
__device__ __forceinline__ void edge_sd(const int* ei, int e, int& s, int& d){
  if (g_is64){ s = ei[2 * e]; d = ei[2 * (N_EDGES + e)]; }
  else       { s = ei[e];     d = ei[N_EDGES + e]; }
  s = clampi(s); d = clampi(d);
}

struct Ptrs { const void* p[8]; };

// pack (k, n) of a [K][Nc] weight into MFMA B-fragment order
__device__ __forceinline__ int wpack(int k, int n, int Nc){
  return (((k >> 5) * (Nc / 16) + (n >> 4)) * 64 + (((k >> 3) & 3) * 16 + (n & 15))) * 8 + (k & 7);
}

// =======================================================================
// prep_k: probe publish + cursor zero + weight pack, ONE dispatch.
// (alpha accumulators no longer need zeroing: gemm1/aggemm plain-store them)
// =======================================================================
#define PREP_Z  N_NODES
#define PREP_W1 (C_IN * C_HID)
#define PREP_W2 (C_HID * C_OUT)
#define PREP_T  (PREP_Z + PREP_W1 + PREP_W2 + 2 * C_HID + C_HID + 2 * C_OUT + C_OUT)

__global__ void prep_k(const unsigned int* __restrict__ xw,
                       const int* __restrict__ ei, Ptrs ps){
  __shared__ int s_isf32;
  if (threadIdx.x < 64){
    int lane = (int)threadIdx.x, cnt = 0;
    for (int j = lane; j < 256; j += 64){
      unsigned int e = (xw[j] >> 7) & 0xFFu;
      if (e >= 0x60u && e <= 0x8Fu) ++cnt;
    }
#pragma unroll
    for (int o = 32; o > 0; o >>= 1) cnt += __shfl_xor(cnt, o, 64);
    if (lane == 0) s_isf32 = (cnt < 200) ? 1 : 0;  // bf16 ~256 in-win; fp32 ~48
  }
  __syncthreads();
  const int isf32 = s_isf32;

  if (blockIdx.x == 0 && threadIdx.x < 64){        // publish for later dispatches
    unsigned long long anybad = __ballot(ei[2 * (int)threadIdx.x + 1] != 0);
    if (threadIdx.x == 0){ g_isf32 = isf32; g_is64 = (anybad == 0ULL) ? 1 : 0; }
  }

  int tid = (int)(blockIdx.x * blockDim.x + threadIdx.x);
  if (tid < PREP_Z){
    g_cursor[tid] = 0;
    return;
  }
  int j = tid - PREP_Z;
  auto ld = [&](const void* p, int i) -> float {
    return isf32 ? ((const float*)p)[i] : bf2f(((const unsigned short*)p)[i]);
  };
  if (j < PREP_W1){
    float f = ld(ps.p[0], j);
    int k = j / C_HID, n = j % C_HID;
    int idx = wpack(k, n, C_HID);
    unsigned short h = f2bf(f);
    c_W1h[idx] = h; c_W1l[idx] = f2bf(f - bf2f(h));
    return;
  }
  j -= PREP_W1;
  if (j < PREP_W2){
    float f = ld(ps.p[4], j);
    int k = j / C_OUT, n = j % C_OUT;
    int idx = wpack(k, n, C_OUT);
    unsigned short h = f2bf(f);
    c_W2h[idx] = h; c_W2l[idx] = f2bf(f - bf2f(h));
    return;
  }
  j -= PREP_W2;
  if      (j <  256) c_as1f[j]        = ld(ps.p[1], j);
  else if (j <  512) c_ad1f[j - 256]  = ld(ps.p[2], j - 256);
  else if (j <  768) c_b1f [j - 512]  = ld(ps.p[3], j - 512);
  else if (j <  896) c_as2f[j - 768]  = ld(ps.p[5], j - 768);
  else if (j < 1024) c_ad2f[j - 896]  = ld(ps.p[6], j - 896);
  else if (j < 1152) c_b2f [j - 1024] = ld(ps.p[7], j - 1024);
}

// ---------------- layer-1 split-bf16 MFMA GEMM + fused alpha epilogue ----------------
// Blocks [0,625) do gemm1; blocks [625,1875) scatter edges into the padded CSR
// (independent work, overlapped in one dispatch).
// Each gemm block owns complete rows (all 256 cols) -> alpha sums via LDS
// cross-wave reduce + plain store: no atomics, no pre-zeroing dependency.
__global__ __launch_bounds__(256) void gemm1_k(const void* __restrict__ xsrc,
                                               const int* __restrict__ ei){
  if (blockIdx.x >= GEMM1_BLKS){   // ---- scatter part ----
    int e = (int)(blockIdx.x - GEMM1_BLKS) * 256 + (int)threadIdx.x;
    if (e < N_EDGES){
      int s, d;
      edge_sd(ei, e, s, d);
      int pos = atomicAdd(&g_cursor[d], 1);
      if (pos < CAP) g_srcidx[(size_t)d * CAP + pos] = s;  // clamp: memory-safe
    }
    return;
  }

  __shared__ float s_ps[4][32], s_pd[4][32];

  const bool isf32 = (g_isf32 != 0);
  int wid  = (int)(threadIdx.x >> 6);
  int lane = (int)(threadIdx.x & 63);
  int kgrp = lane >> 4, cl = lane & 15;
  int mbase = blockIdx.x * 32;

  f32x4 acc[2][4];
#pragma unroll
  for (int m = 0; m < 2; ++m)
#pragma unroll
    for (int n = 0; n < 4; ++n) acc[m][n] = (f32x4){0.f, 0.f, 0.f, 0.f};

  for (int kt = 0; kt < 8; ++kt){
    int kbase = kt * 32 + kgrp * 8;
    bf16x8 ah[2], al[2];
    if (isf32){
      const float* Xf = (const float*)xsrc;
#pragma unroll
      for (int m = 0; m < 2; ++m){
        const float4* xp = (const float4*)(Xf + (size_t)(mbase + m * 16 + cl) * 256 + kbase);
        float4 v0 = xp[0], v1 = xp[1];
        float vals[8] = {v0.x, v0.y, v0.z, v0.w, v1.x, v1.y, v1.z, v1.w};
#pragma unroll
        for (int j = 0; j < 8; ++j){
          unsigned short h = f2bf(vals[j]);
          ah[m][j] = (short)h;
          al[m][j] = (short)f2bf(vals[j] - bf2f(h));
        }
      }
    } else {  // bf16 input: lo part is zero
      const unsigned short* Xb = (const unsigned short*)xsrc;
#pragma unroll
      for (int m = 0; m < 2; ++m){
        ah[m] = *(const bf16x8*)(Xb + (size_t)(mbase + m * 16 + cl) * 256 + kbase);
        al[m] = (bf16x8){0,0,0,0,0,0,0,0};
      }
    }
#pragma unroll
    for (int nn = 0; nn < 4; ++nn){
      int nt = wid * 4 + nn;
      size_t wi = ((size_t)(kt * 16 + nt) * 64 + lane) * 8;   // Nc/16 = 16
      bf16x8 bh = *(const bf16x8*)(c_W1h + wi);
      bf16x8 bl = *(const bf16x8*)(c_W1l + wi);
#pragma unroll
      for (int m = 0; m < 2; ++m){
        acc[m][nn] = __builtin_amdgcn_mfma_f32_16x16x32_bf16(ah[m], bh, acc[m][nn], 0, 0, 0);
        acc[m][nn] = __builtin_amdgcn_mfma_f32_16x16x32_bf16(ah[m], bl, acc[m][nn], 0, 0, 0);
        acc[m][nn] = __builtin_amdgcn_mfma_f32_16x16x32_bf16(al[m], bh, acc[m][nn], 0, 0, 0);
      }
    }
  }

  float asv[4], adv[4];
#pragma unroll
  for (int nn = 0; nn < 4; ++nn){
    int col = (wid * 4 + nn) * 16 + cl;
    asv[nn] = c_as1f[col]; adv[nn] = c_ad1f[col];
  }
#pragma unroll
  for (int m = 0; m < 2; ++m){
#pragma unroll
    for (int i = 0; i < 4; ++i){
      int rl = m * 16 + kgrp * 4 + i;        // row-local in [0,32)
      int row = mbase + rl;
      float ps = 0.f, pd = 0.f;
#pragma unroll
      for (int nn = 0; nn < 4; ++nn){
        int col = (wid * 4 + nn) * 16 + cl;
        float v = acc[m][nn][i];
        g_h1b[(size_t)row * C_HID + col] = f2bf(v);
        ps += v * asv[nn]; pd += v * adv[nn];
      }
      ps += __shfl_xor(ps, 1);  pd += __shfl_xor(pd, 1);
      ps += __shfl_xor(ps, 2);  pd += __shfl_xor(pd, 2);
      ps += __shfl_xor(ps, 4);  pd += __shfl_xor(pd, 4);
      ps += __shfl_xor(ps, 8);  pd += __shfl_xor(pd, 8);
      if (cl == 0){ s_ps[wid][rl] = ps; s_pd[wid][rl] = pd; }
    }
  }
  __syncthreads();
  if (threadIdx.x < 32){
    int r = (int)threadIdx.x;
    g_alps1[mbase + r] = s_ps[0][r] + s_ps[1][r] + s_ps[2][r] + s_ps[3][r];
    g_alpd1[mbase + r] = s_pd[0][r] + s_pd[1][r] + s_pd[2][r] + s_pd[3][r];
  }
}

#define ACC8(p, ww) { \
  a0 += (ww) * bf2f((unsigned short)((p).x & 0xFFFFu)); \
  a1 += (ww) * bf2f((unsigned short)((p).x >> 16)); \
  a2 += (ww) * bf2f((unsigned short)((p).y & 0xFFFFu)); \
  a3 += (ww) * bf2f((unsigned short)((p).y >> 16)); \
  a4 += (ww) * bf2f((unsigned short)((p).z & 0xFFFFu)); \
  a5 += (ww) * bf2f((unsigned short)((p).z >> 16)); \
  a6 += (ww) * bf2f((unsigned short)((p).w & 0xFFFFu)); \
  a7 += (ww) * bf2f((unsigned short)((p).w >> 16)); }

#define ACC4(p, ww) { \
  a0 += (ww) * bf2f((unsigned short)((p).x & 0xFFFFu)); \
  a1 += (ww) * bf2f((unsigned short)((p).x >> 16)); \
  a2 += (ww) * bf2f((unsigned short)((p).y & 0xFFFFu)); \
  a3 += (ww) * bf2f((unsigned short)((p).y >> 16)); }

// =======================================================================
// aggemm_k: layer-1 softmax+aggregation FUSED with gemm2.
// Phase 1 uses HALF-WAVE pairing: lanes 0-31 serve node A, lanes 32-63 node B;
// one uint4 row-gather instruction fetches 512B of A's row AND 512B of B's row
// -> per-edge wave-instruction count ~halved, 2 independent gather chains.
// Out-of-range lanes gather the node's own (L1-hot) row with weight 0.
// =======================================================================
__global__ __launch_bounds__(256) void aggemm_k(){
  __shared__ __align__(16) unsigned short s_hi[16 * AGG_PAD];
  __shared__ __align__(16) unsigned short s_lo[16 * AGG_PAD];
  __shared__ float s_ps[4][16], s_pd[4][16];

  int lane = (int)(threadIdx.x & 63);
  int wid  = (int)(threadIdx.x >> 6);
  int hl   = lane & 31;         // lane within half-wave
  int half = lane >> 5;         // 0: node A, 1: node B
  int nb   = blockIdx.x * 16;
  const uint4* H4 = (const uint4*)g_h1b;   // row = 32 x uint4 (512 B)

  // ---- phase 1: each wave aggregates 2 node-pairs (4 nodes) ----
  for (int q = 0; q < 2; ++q){
    int n = nb + wid * 4 + 2 * q + half;
    int len = g_cursor[n]; if (len > CAP) len = CAP;
    int lenmax; { int lo = __shfl_xor(len, 32); lenmax = lo > len ? lo : len; }
    float adn = g_alpd1[n];
    float a0 = 0.f, a1 = 0.f, a2 = 0.f, a3 = 0.f;
    float a4 = 0.f, a5 = 0.f, a6 = 0.f, a7 = 0.f;

    // implicit self-loop: source row = n
    float es = g_alps1[n] + adn;
    es = (es > 0.f) ? es : NEG_SLOPE * es;
    float wself = __expf(es);
    float dpart = (hl == 0) ? wself : 0.f;
    {
      uint4 p = H4[(size_t)n * 32 + hl];
      ACC8(p, wself)
    }

    for (int base = 0; base < lenmax; base += 32){
      int rem = len - base;
      int nv = rem < 0 ? 0 : (rem > 32 ? 32 : rem);
      int remx = lenmax - base;
      int nvmax = remx > 32 ? 32 : remx;
      int sv = n; float wv = 0.f;                 // inert fallback: own row, w=0
      if (hl < nv){
        sv = g_srcidx[(size_t)n * CAP + base + hl];
        float e = g_alps1[sv] + adn;
        e = (e > 0.f) ? e : NEG_SLOPE * e;
        wv = __expf(e);
      }
      dpart += wv;
      int j = 0;
      for (; j + 4 <= nvmax; j += 4){
        int s0 = __shfl(sv, j, 32),     s1 = __shfl(sv, j + 1, 32);
        int s2 = __shfl(sv, j + 2, 32), s3 = __shfl(sv, j + 3, 32);
        float w0 = __shfl(wv, j, 32),     w1 = __shfl(wv, j + 1, 32);
        float w2 = __shfl(wv, j + 2, 32), w3 = __shfl(wv, j + 3, 32);
        uint4 p0 = H4[(size_t)s0 * 32 + hl];
        uint4 p1 = H4[(size_t)s1 * 32 + hl];
        uint4 p2 = H4[(size_t)s2 * 32 + hl];
        uint4 p3 = H4[(size_t)s3 * 32 + hl];
        ACC8(p0, w0) ACC8(p1, w1) ACC8(p2, w2) ACC8(p3, w3)
      }
      for (; j < nvmax; ++j){
        int s = __shfl(sv, j, 32);
        float w = __shfl(wv, j, 32);
        uint4 p = H4[(size_t)s * 32 + hl];
        ACC8(p, w)
      }
    }

    float den = dpart;
#pragma unroll
    for (int o = 16; o > 0; o >>= 1) den += __shfl_xor(den, o, 32);
    float inv = 1.f / den;

    float o0 = a0 * inv + c_b1f[8 * hl];
    float o1 = a1 * inv + c_b1f[8 * hl + 1];
    float o2 = a2 * inv + c_b1f[8 * hl + 2];
    float o3 = a3 * inv + c_b1f[8 * hl + 3];
    float o4 = a4 * inv + c_b1f[8 * hl + 4];
    float o5 = a5 * inv + c_b1f[8 * hl + 5];
    float o6 = a6 * inv + c_b1f[8 * hl + 6];
    float o7 = a7 * inv + c_b1f[8 * hl + 7];
    o0 = fmaxf(o0, 0.f); o1 = fmaxf(o1, 0.f); o2 = fmaxf(o2, 0.f); o3 = fmaxf(o3, 0.f);
    o4 = fmaxf(o4, 0.f); o5 = fmaxf(o5, 0.f); o6 = fmaxf(o6, 0.f); o7 = fmaxf(o7, 0.f);
    unsigned short h0 = f2bf(o0), h1 = f2bf(o1), h2 = f2bf(o2), h3 = f2bf(o3);
    unsigned short h4 = f2bf(o4), h5 = f2bf(o5), h6 = f2bf(o6), h7 = f2bf(o7);
    uint4 ph, pl;
    ph.x = (unsigned)h0 | ((unsigned)h1 << 16);
    ph.y = (unsigned)h2 | ((unsigned)h3 << 16);
    ph.z = (unsigned)h4 | ((unsigned)h5 << 16);
    ph.w = (unsigned)h6 | ((unsigned)h7 << 16);
    pl.x = (unsigned)f2bf(o0 - bf2f(h0)) | ((unsigned)f2bf(o1 - bf2f(h1)) << 16);
    pl.y = (unsigned)f2bf(o2 - bf2f(h2)) | ((unsigned)f2bf(o3 - bf2f(h3)) << 16);
    pl.z = (unsigned)f2bf(o4 - bf2f(h4)) | ((unsigned)f2bf(o5 - bf2f(h5)) << 16);
    pl.w = (unsigned)f2bf(o6 - bf2f(h6)) | ((unsigned)f2bf(o7 - bf2f(h7)) << 16);
    int r = wid * 4 + 2 * q + half;
    *(uint4*)&s_hi[r * AGG_PAD + 8 * hl] = ph;   // byte off = 560r + 16hl: 16B-aligned
    *(uint4*)&s_lo[r * AGG_PAD + 8 * hl] = pl;
  }
  __syncthreads();

  // ---- phase 2: gemm2 tile, rows [nb, nb+16), cols [0,128), K=256 ----
  int kgrp = lane >> 4, cl = lane & 15;
  f32x4 acc[2];
  acc[0] = (f32x4){0.f, 0.f, 0.f, 0.f};
  acc[1] = (f32x4){0.f, 0.f, 0.f, 0.f};
  for (int kt = 0; kt < 8; ++kt){
    int rb = cl * AGG_PAD + kt * 32 + kgrp * 8;
    bf16x8 ah = *(const bf16x8*)&s_hi[rb];
    bf16x8 al = *(const bf16x8*)&s_lo[rb];
#pragma unroll
    for (int nn = 0; nn < 2; ++nn){
      int nt = wid * 2 + nn;
      size_t wi = ((size_t)(kt * 8 + nt) * 64 + lane) * 8;    // Nc/16 = 8
      bf16x8 bh = *(const bf16x8*)(c_W2h + wi);
      bf16x8 bl = *(const bf16x8*)(c_W2l + wi);
      acc[nn] = __builtin_amdgcn_mfma_f32_16x16x32_bf16(ah, bh, acc[nn], 0, 0, 0);
      acc[nn] = __builtin_amdgcn_mfma_f32_16x16x32_bf16(ah, bl, acc[nn], 0, 0, 0);
      acc[nn] = __builtin_amdgcn_mfma_f32_16x16x32_bf16(al, bh, acc[nn], 0, 0, 0);
    }
  }

  float asv[2], adv[2];
#pragma unroll
  for (int nn = 0; nn < 2; ++nn){
    int col = (wid * 2 + nn) * 16 + cl;
    asv[nn] = c_as2f[col]; adv[nn] = c_ad2f[col];
  }
#pragma unroll
  for (int i = 0; i < 4; ++i){
    int row = nb + kgrp * 4 + i;
    float ps = 0.f, pd = 0.f;
#pragma unroll
    for (int nn = 0; nn < 2; ++nn){
      int col = (wid * 2 + nn) * 16 + cl;
      float v = acc[nn][i];
      g_h2b[(size_t)row * C_OUT + col] = f2bf(v);
      ps += v * asv[nn]; pd += v * adv[nn];
    }
    ps += __shfl_xor(ps, 1);  pd += __shfl_xor(pd, 1);
    ps += __shfl_xor(ps, 2);  pd += __shfl_xor(pd, 2);
    ps += __shfl_xor(ps, 4);  pd += __shfl_xor(pd, 4);
    ps += __shfl_xor(ps, 8);  pd += __shfl_xor(pd, 8);
    if (cl == 0){ s_ps[wid][kgrp * 4 + i] = ps; s_pd[wid][kgrp * 4 + i] = pd; }
  }
  __syncthreads();
  if (threadIdx.x < 16){
    int r = (int)threadIdx.x;
    g_alps2[nb + r] = s_ps[0][r] + s_ps[1][r] + s_ps[2][r] + s_ps[3][r];
    g_alpd2[nb + r] = s_pd[0][r] + s_pd[1][r] + s_pd[2][r] + s_pd[3][r];
  }
}

// ---------------- layer-2 softmax + aggregation: half-wave pairing ----------------
// lanes 0-31: node A (uint2 x 32 = 256 B row), lanes 32-63: node B.
__global__ __launch_bounds__(256) void agg2_k(float* OUT){
  int lane = (int)(threadIdx.x & 63);
  int wid  = (int)(threadIdx.x >> 6);
  int hl   = lane & 31;
  int half = lane >> 5;
  int n = blockIdx.x * 8 + wid * 2 + half;
  const uint2* H2 = (const uint2*)g_h2b;    // row = 32 x uint2 (256 B)

  int len = g_cursor[n]; if (len > CAP) len = CAP;
  int lenmax; { int lo = __shfl_xor(len, 32); lenmax = lo > len ? lo : len; }
  float adn = g_alpd2[n];
  float a0 = 0.f, a1 = 0.f, a2 = 0.f, a3 = 0.f;

  // implicit self-loop
  float es = g_alps2[n] + adn;
  es = (es > 0.f) ? es : NEG_SLOPE * es;
  float wself = __expf(es);
  float dpart = (hl == 0) ? wself : 0.f;
  {
    uint2 p = H2[(size_t)n * 32 + hl];
    ACC4(p, wself)
  }

  for (int base = 0; base < lenmax; base += 32){
    int rem = len - base;
    int nv = rem < 0 ? 0 : (rem > 32 ? 32 : rem);
    int remx = lenmax - base;
    int nvmax = remx > 32 ? 32 : remx;
    int sv = n; float wv = 0.f;
    if (hl < nv){
      sv = g_srcidx[(size_t)n * CAP + base + hl];
      float e = g_alps2[sv] + adn;
      e = (e > 0.f) ? e : NEG_SLOPE * e;
      wv = __expf(e);
    }
    dpart += wv;
    int j = 0;
    for (; j + 8 <= nvmax; j += 8){
      int s0 = __shfl(sv, j, 32),     s1 = __shfl(sv, j + 1, 32);
      int s2 = __shfl(sv, j + 2, 32), s3 = __shfl(sv, j + 3, 32);
      int s4 = __shfl(sv, j + 4, 32), s5 = __shfl(sv, j + 5, 32);
      int s6 = __shfl(sv, j + 6, 32), s7 = __shfl(sv, j + 7, 32);
      float w0 = __shfl(wv, j, 32),     w1 = __shfl(wv, j + 1, 32);
      float w2 = __shfl(wv, j + 2, 32), w3 = __shfl(wv, j + 3, 32);
      float w4 = __shfl(wv, j + 4, 32), w5 = __shfl(wv, j + 5, 32);
      float w6 = __shfl(wv, j + 6, 32), w7 = __shfl(wv, j + 7, 32);
      uint2 p0 = H2[(size_t)s0 * 32 + hl];
      uint2 p1 = H2[(size_t)s1 * 32 + hl];
      uint2 p2 = H2[(size_t)s2 * 32 + hl];
      uint2 p3 = H2[(size_t)s3 * 32 + hl];
      uint2 p4 = H2[(size_t)s4 * 32 + hl];
      uint2 p5 = H2[(size_t)s5 * 32 + hl];
      uint2 p6 = H2[(size_t)s6 * 32 + hl];
      uint2 p7 = H2[(size_t)s7 * 32 + hl];
      ACC4(p0, w0) ACC4(p1, w1) ACC4(p2, w2) ACC4(p3, w3)
      ACC4(p4, w4) ACC4(p5, w5) ACC4(p6, w6) ACC4(p7, w7)
    }
    for (; j + 4 <= nvmax; j += 4){
      int s0 = __shfl(sv, j, 32),     s1 = __shfl(sv, j + 1, 32);
      int s2 = __shfl(sv, j + 2, 32), s3 = __shfl(sv, j + 3, 32);
      float w0 = __shfl(wv, j, 32),     w1 = __shfl(wv, j + 1, 32);
      float w2 = __shfl(wv, j + 2, 32), w3 = __shfl(wv, j + 3, 32);
      uint2 p0 = H2[(size_t)s0 * 32 + hl];
      uint2 p1 = H2[(size_t)s1 * 32 + hl];
      uint2 p2 = H2[(size_t)s2 * 32 + hl];
      uint2 p3 = H2[(size_t)s3 * 32 + hl];
      ACC4(p0, w0) ACC4(p1, w1) ACC4(p2, w2) ACC4(p3, w3)
    }
    for (; j < nvmax; ++j){
      int s = __shfl(sv, j, 32);
      float w = __shfl(wv, j, 32);
      uint2 p = H2[(size_t)s * 32 + hl];
      ACC4(p, w)
    }
  }

  float den = dpart;
#pragma unroll
  for (int o = 16; o > 0; o >>= 1) den += __shfl_xor(den, o, 32);
  float inv = 1.f / den;

  float4 o;
  o.x = a0 * inv + c_b2f[4 * hl];
  o.y = a1 * inv + c_b2f[4 * hl + 1];
  o.z = a2 * inv + c_b2f[4 * hl + 2];
  o.w = a3 * inv + c_b2f[4 * hl + 3];
  ((float4*)OUT)[(size_t)n * 32 + hl] = o;
}

extern "C" void kernel_launch(void* const* d_in, const int* in_sizes, int n_in,
                              void* d_out, int out_size, void* d_ws, size_t ws_size,
                              hipStream_t stream){
  (void)in_sizes; (void)n_in; (void)out_size; (void)d_ws; (void)ws_size;
  const void* x  = d_in[0];
  const int*  ei = (const int*)d_in[1];
  float* out = (float*)d_out;

  Ptrs ps;
  ps.p[0] = d_in[2]; ps.p[1] = d_in[3]; ps.p[2] = d_in[4]; ps.p[3] = d_in[5];
  ps.p[4] = d_in[6]; ps.p[5] = d_in[7]; ps.p[6] = d_in[8]; ps.p[7] = d_in[9];

  prep_k<<<(PREP_T + 255) / 256, 256, 0, stream>>>((const unsigned int*)x, ei, ps);

  // ---- layer 1: gemm1 + edge scatter fused (independent work, one dispatch) ----
  gemm1_k<<<GEMM1_BLKS + SCAT_BLKS, 256, 0, stream>>>(x, ei);

  // ---- agg1 + gemm2 fused (row-aligned dependency -> in-block via LDS) ----
  aggemm_k<<<N_NODES / 16, 256, 0, stream>>>();

  // ---- layer 2 aggregation ----
  agg2_k<<<N_NODES / 8, 256, 0, stream>>>(out);
}

// Round 3
// 163.556 us; speedup vs baseline: 1.0435x; 1.0435x over previous
//
#include <hip/hip_runtime.h>
#include <math.h>

#define N_NODES 20000
#define N_EDGES 320000
#define C_IN  256
#define C_HID 256
#define C_OUT 128
#define NEG_SLOPE 0.2f
#define CAP   256   // padded-CSR slots per node (real edges only; self-loop implicit)
#define GEMM1_BLKS (N_NODES / 32)          // 625
#define SCAT_BLKS  ((N_EDGES + 255) / 256) // 1250
#define AGG_PAD 280 // 256 + 24: LDS row stride (560 B = 16B-aligned, 8 bank-start groups)

typedef __attribute__((ext_vector_type(8))) short bf16x8;
typedef __attribute__((ext_vector_type(4))) float f32x4;

// ---- all scratch in module globals (ws_size unknown; globals are safe) ----
__device__ __align__(16) unsigned short c_W1h[C_IN * C_HID], c_W1l[C_IN * C_HID];
__device__ __align__(16) unsigned short c_W2h[C_HID * C_OUT], c_W2l[C_HID * C_OUT];
__device__ float c_as1f[C_HID], c_ad1f[C_HID], c_b1f[C_HID];
__device__ float c_as2f[C_OUT], c_ad2f[C_OUT], c_b2f[C_OUT];
__device__ __align__(16) unsigned short g_h1b[(size_t)N_NODES * C_HID]; // h1 bf16
__device__ __align__(16) unsigned short g_h2b[(size_t)N_NODES * C_OUT]; // h2 bf16
__device__ float g_alps1[N_NODES], g_alpd1[N_NODES];
__device__ float g_alps2[N_NODES], g_alpd2[N_NODES];
__device__ int   g_cursor[N_NODES];            // per-node real-edge count
__device__ int   g_srcidx[(size_t)N_NODES * CAP];
__device__ int   g_is64;    // edge_index arrived as raw int64 words
__device__ int   g_isf32;   // float inputs arrived as raw fp32 words

__device__ __forceinline__ float bf2f(unsigned short b){
  unsigned int u = ((unsigned int)b) << 16;
  return __builtin_bit_cast(float, u);
}
__device__ __forceinline__ unsigned short f2bf(float f){
  unsigned int u = __builtin_bit_cast(unsigned int, f);
  u += 0x7fffu + ((u >> 16) & 1u);   // round-to-nearest-even
  return (unsigned short)(u >> 16);
}
__device__ __forceinline__ int clampi(int v){
  v = v < 0 ? 0 : v;
  return v >= N_NODES ? N_NODES - 1 : v;
}
__device__ __forceinline__ void edge_sd(const int* ei, int e, int& s, int& d){
  if (g_is64){ s = ei[2 * e]; d = ei[2 * (N_EDGES + e)]; }
  else       { s = ei[e];     d = ei[N_EDGES + e]; }
  s = clampi(s); d = clampi(d);
}

struct Ptrs { const void* p[8]; };

// pack (k, n) of a [K][Nc] weight into MFMA B-fragment order
__device__ __forceinline__ int wpack(int k, int n, int Nc){
  return (((k >> 5) * (Nc / 16) + (n >> 4)) * 64 + (((k >> 3) & 3) * 16 + (n & 15))) * 8 + (k & 7);
}

// =======================================================================
// prep_k: probe publish + cursor zero + weight pack, ONE dispatch.
// (alpha accumulators need no zeroing: gemm1/aggemm plain-store them)
// =======================================================================
#define PREP_Z  N_NODES
#define PREP_W1 (C_IN * C_HID)
#define PREP_W2 (C_HID * C_OUT)
#define PREP_T  (PREP_Z + PREP_W1 + PREP_W2 + 2 * C_HID + C_HID + 2 * C_OUT + C_OUT)

__global__ void prep_k(const unsigned int* __restrict__ xw,
                       const int* __restrict__ ei, Ptrs ps){
  __shared__ int s_isf32;
  if (threadIdx.x < 64){
    int lane = (int)threadIdx.x, cnt = 0;
    for (int j = lane; j < 256; j += 64){
      unsigned int e = (xw[j] >> 7) & 0xFFu;
      if (e >= 0x60u && e <= 0x8Fu) ++cnt;
    }
#pragma unroll
    for (int o = 32; o > 0; o >>= 1) cnt += __shfl_xor(cnt, o, 64);
    if (lane == 0) s_isf32 = (cnt < 200) ? 1 : 0;  // bf16 ~256 in-win; fp32 ~48
  }
  __syncthreads();
  const int isf32 = s_isf32;

  if (blockIdx.x == 0 && threadIdx.x < 64){        // publish for later dispatches
    unsigned long long anybad = __ballot(ei[2 * (int)threadIdx.x + 1] != 0);
    if (threadIdx.x == 0){ g_isf32 = isf32; g_is64 = (anybad == 0ULL) ? 1 : 0; }
  }

  int tid = (int)(blockIdx.x * blockDim.x + threadIdx.x);
  if (tid < PREP_Z){
    g_cursor[tid] = 0;
    return;
  }
  int j = tid - PREP_Z;
  auto ld = [&](const void* p, int i) -> float {
    return isf32 ? ((const float*)p)[i] : bf2f(((const unsigned short*)p)[i]);
  };
  if (j < PREP_W1){
    float f = ld(ps.p[0], j);
    int k = j / C_HID, n = j % C_HID;
    int idx = wpack(k, n, C_HID);
    unsigned short h = f2bf(f);
    c_W1h[idx] = h; c_W1l[idx] = f2bf(f - bf2f(h));
    return;
  }
  j -= PREP_W1;
  if (j < PREP_W2){
    float f = ld(ps.p[4], j);
    int k = j / C_OUT, n = j % C_OUT;
    int idx = wpack(k, n, C_OUT);
    unsigned short h = f2bf(f);
    c_W2h[idx] = h; c_W2l[idx] = f2bf(f - bf2f(h));
    return;
  }
  j -= PREP_W2;
  if      (j <  256) c_as1f[j]        = ld(ps.p[1], j);
  else if (j <  512) c_ad1f[j - 256]  = ld(ps.p[2], j - 256);
  else if (j <  768) c_b1f [j - 512]  = ld(ps.p[3], j - 512);
  else if (j <  896) c_as2f[j - 768]  = ld(ps.p[5], j - 768);
  else if (j < 1024) c_ad2f[j - 896]  = ld(ps.p[6], j - 896);
  else if (j < 1152) c_b2f [j - 1024] = ld(ps.p[7], j - 1024);
}

// ---------------- layer-1 split-bf16 MFMA GEMM + fused alpha epilogue ----------------
// Blocks [0,625) do gemm1; blocks [625,1875) scatter edges into the padded CSR
// (independent work, overlapped in one dispatch).
// Each gemm block owns complete rows (all 256 cols) -> alpha sums via LDS
// cross-wave reduce + plain store: no atomics, no pre-zeroing dependency.
__global__ __launch_bounds__(256) void gemm1_k(const void* __restrict__ xsrc,
                                               const int* __restrict__ ei){
  if (blockIdx.x >= GEMM1_BLKS){   // ---- scatter part ----
    int e = (int)(blockIdx.x - GEMM1_BLKS) * 256 + (int)threadIdx.x;
    if (e < N_EDGES){
      int s, d;
      edge_sd(ei, e, s, d);
      int pos = atomicAdd(&g_cursor[d], 1);
      if (pos < CAP) g_srcidx[(size_t)d * CAP + pos] = s;  // clamp: memory-safe
    }
    return;
  }

  __shared__ float s_ps[4][32], s_pd[4][32];

  const bool isf32 = (g_isf32 != 0);
  int wid  = (int)(threadIdx.x >> 6);
  int lane = (int)(threadIdx.x & 63);
  int kgrp = lane >> 4, cl = lane & 15;
  int mbase = blockIdx.x * 32;

  f32x4 acc[2][4];
#pragma unroll
  for (int m = 0; m < 2; ++m)
#pragma unroll
    for (int n = 0; n < 4; ++n) acc[m][n] = (f32x4){0.f, 0.f, 0.f, 0.f};

  for (int kt = 0; kt < 8; ++kt){
    int kbase = kt * 32 + kgrp * 8;
    bf16x8 ah[2], al[2];
    if (isf32){
      const float* Xf = (const float*)xsrc;
#pragma unroll
      for (int m = 0; m < 2; ++m){
        const float4* xp = (const float4*)(Xf + (size_t)(mbase + m * 16 + cl) * 256 + kbase);
        float4 v0 = xp[0], v1 = xp[1];
        float vals[8] = {v0.x, v0.y, v0.z, v0.w, v1.x, v1.y, v1.z, v1.w};
#pragma unroll
        for (int j = 0; j < 8; ++j){
          unsigned short h = f2bf(vals[j]);
          ah[m][j] = (short)h;
          al[m][j] = (short)f2bf(vals[j] - bf2f(h));
        }
      }
    } else {  // bf16 input: lo part is zero
      const unsigned short* Xb = (const unsigned short*)xsrc;
#pragma unroll
      for (int m = 0; m < 2; ++m){
        ah[m] = *(const bf16x8*)(Xb + (size_t)(mbase + m * 16 + cl) * 256 + kbase);
        al[m] = (bf16x8){0,0,0,0,0,0,0,0};
      }
    }
#pragma unroll
    for (int nn = 0; nn < 4; ++nn){
      int nt = wid * 4 + nn;
      size_t wi = ((size_t)(kt * 16 + nt) * 64 + lane) * 8;   // Nc/16 = 16
      bf16x8 bh = *(const bf16x8*)(c_W1h + wi);
      bf16x8 bl = *(const bf16x8*)(c_W1l + wi);
#pragma unroll
      for (int m = 0; m < 2; ++m){
        acc[m][nn] = __builtin_amdgcn_mfma_f32_16x16x32_bf16(ah[m], bh, acc[m][nn], 0, 0, 0);
        acc[m][nn] = __builtin_amdgcn_mfma_f32_16x16x32_bf16(ah[m], bl, acc[m][nn], 0, 0, 0);
        acc[m][nn] = __builtin_amdgcn_mfma_f32_16x16x32_bf16(al[m], bh, acc[m][nn], 0, 0, 0);
      }
    }
  }

  float asv[4], adv[4];
#pragma unroll
  for (int nn = 0; nn < 4; ++nn){
    int col = (wid * 4 + nn) * 16 + cl;
    asv[nn] = c_as1f[col]; adv[nn] = c_ad1f[col];
  }
#pragma unroll
  for (int m = 0; m < 2; ++m){
#pragma unroll
    for (int i = 0; i < 4; ++i){
      int rl = m * 16 + kgrp * 4 + i;        // row-local in [0,32)
      int row = mbase + rl;
      float ps = 0.f, pd = 0.f;
#pragma unroll
      for (int nn = 0; nn < 4; ++nn){
        int col = (wid * 4 + nn) * 16 + cl;
        float v = acc[m][nn][i];
        g_h1b[(size_t)row * C_HID + col] = f2bf(v);
        ps += v * asv[nn]; pd += v * adv[nn];
      }
      ps += __shfl_xor(ps, 1);  pd += __shfl_xor(pd, 1);
      ps += __shfl_xor(ps, 2);  pd += __shfl_xor(pd, 2);
      ps += __shfl_xor(ps, 4);  pd += __shfl_xor(pd, 4);
      ps += __shfl_xor(ps, 8);  pd += __shfl_xor(pd, 8);
      if (cl == 0){ s_ps[wid][rl] = ps; s_pd[wid][rl] = pd; }
    }
  }
  __syncthreads();
  if (threadIdx.x < 32){
    int r = (int)threadIdx.x;
    g_alps1[mbase + r] = s_ps[0][r] + s_ps[1][r] + s_ps[2][r] + s_ps[3][r];
    g_alpd1[mbase + r] = s_pd[0][r] + s_pd[1][r] + s_pd[2][r] + s_pd[3][r];
  }
}

#define ACC4(p, ww) { \
  a0 += (ww) * bf2f((unsigned short)((p).x & 0xFFFFu)); \
  a1 += (ww) * bf2f((unsigned short)((p).x >> 16)); \
  a2 += (ww) * bf2f((unsigned short)((p).y & 0xFFFFu)); \
  a3 += (ww) * bf2f((unsigned short)((p).y >> 16)); }

#define ACC2(p, ww) { \
  a0 += (ww) * bf2f((unsigned short)((p) & 0xFFFFu)); \
  a1 += (ww) * bf2f((unsigned short)((p) >> 16)); }

// =======================================================================
// aggemm_k: layer-1 softmax+aggregation FUSED with gemm2 (R1-proven bodies).
// Gather is FULL-WAVE: 64 lanes x 8B = one 512B h1 row per load instruction;
// zero inert lanes, zero extra traffic (R2's pairing experiment showed the
// phase is L2/L3-traffic-bound, so traffic discipline wins over issue count).
// =======================================================================
__global__ __launch_bounds__(256) void aggemm_k(){
  __shared__ __align__(16) unsigned short s_hi[16 * AGG_PAD];
  __shared__ __align__(16) unsigned short s_lo[16 * AGG_PAD];
  __shared__ float s_ps[4][16], s_pd[4][16];

  int lane = (int)(threadIdx.x & 63);
  int wid  = (int)(threadIdx.x >> 6);
  int nb   = blockIdx.x * 16;
  const uint2* H2 = (const uint2*)g_h1b;

  // ---- phase 1: each wave aggregates 4 nodes ----
  for (int q = 0; q < 4; ++q){
    int n = nb + wid * 4 + q;
    int len = g_cursor[n]; if (len > CAP) len = CAP;
    int i0 = n * CAP, i1 = i0 + len;
    float adn = g_alpd1[n];
    float dpart = 0.f;
    float a0 = 0.f, a1 = 0.f, a2 = 0.f, a3 = 0.f;

    { // implicit self-loop: source row = n
      float es = g_alps1[n] + adn;
      es = (es > 0.f) ? es : NEG_SLOPE * es;
      float wself = __expf(es);
      if (lane == 0) dpart += wself;
      uint2 p = H2[(size_t)n * 64 + lane];
      ACC4(p, wself)
    }

    for (int base = i0; base < i1; base += 64){
      int nv = i1 - base; if (nv > 64) nv = 64;
      int sv = 0; float wv = 0.f;
      if (lane < nv){
        sv = g_srcidx[base + lane];
        float e = g_alps1[sv] + adn;
        e = (e > 0.f) ? e : NEG_SLOPE * e;
        wv = __expf(e);
      }
      dpart += wv;
      int j = 0;
      for (; j + 8 <= nv; j += 8){
        int s0 = __shfl(sv, j),     s1 = __shfl(sv, j + 1);
        int s2 = __shfl(sv, j + 2), s3 = __shfl(sv, j + 3);
        int s4 = __shfl(sv, j + 4), s5 = __shfl(sv, j + 5);
        int s6 = __shfl(sv, j + 6), s7 = __shfl(sv, j + 7);
        float w0 = __shfl(wv, j),     w1 = __shfl(wv, j + 1);
        float w2 = __shfl(wv, j + 2), w3 = __shfl(wv, j + 3);
        float w4 = __shfl(wv, j + 4), w5 = __shfl(wv, j + 5);
        float w6 = __shfl(wv, j + 6), w7 = __shfl(wv, j + 7);
        uint2 p0 = H2[(size_t)s0 * 64 + lane];
        uint2 p1 = H2[(size_t)s1 * 64 + lane];
        uint2 p2 = H2[(size_t)s2 * 64 + lane];
        uint2 p3 = H2[(size_t)s3 * 64 + lane];
        uint2 p4 = H2[(size_t)s4 * 64 + lane];
        uint2 p5 = H2[(size_t)s5 * 64 + lane];
        uint2 p6 = H2[(size_t)s6 * 64 + lane];
        uint2 p7 = H2[(size_t)s7 * 64 + lane];
        ACC4(p0, w0) ACC4(p1, w1) ACC4(p2, w2) ACC4(p3, w3)
        ACC4(p4, w4) ACC4(p5, w5) ACC4(p6, w6) ACC4(p7, w7)
      }
      for (; j + 4 <= nv; j += 4){
        int s0 = __shfl(sv, j),     s1 = __shfl(sv, j + 1);
        int s2 = __shfl(sv, j + 2), s3 = __shfl(sv, j + 3);
        float w0 = __shfl(wv, j),     w1 = __shfl(wv, j + 1);
        float w2 = __shfl(wv, j + 2), w3 = __shfl(wv, j + 3);
        uint2 p0 = H2[(size_t)s0 * 64 + lane];
        uint2 p1 = H2[(size_t)s1 * 64 + lane];
        uint2 p2 = H2[(size_t)s2 * 64 + lane];
        uint2 p3 = H2[(size_t)s3 * 64 + lane];
        ACC4(p0, w0) ACC4(p1, w1) ACC4(p2, w2) ACC4(p3, w3)
      }
      for (; j < nv; ++j){
        int s = __shfl(sv, j);
        float w = __shfl(wv, j);
        uint2 p = H2[(size_t)s * 64 + lane];
        ACC4(p, w)
      }
    }

    float den = dpart;
#pragma unroll
    for (int o = 32; o > 0; o >>= 1) den += __shfl_xor(den, o, 64);
    float inv = 1.f / den;

    float o0 = a0 * inv + c_b1f[4 * lane];
    float o1 = a1 * inv + c_b1f[4 * lane + 1];
    float o2 = a2 * inv + c_b1f[4 * lane + 2];
    float o3 = a3 * inv + c_b1f[4 * lane + 3];
    o0 = fmaxf(o0, 0.f); o1 = fmaxf(o1, 0.f);
    o2 = fmaxf(o2, 0.f); o3 = fmaxf(o3, 0.f);
    unsigned short h0 = f2bf(o0), h1 = f2bf(o1), h2 = f2bf(o2), h3 = f2bf(o3);
    uint2 ph, pl;
    ph.x = (unsigned)h0 | ((unsigned)h1 << 16);
    ph.y = (unsigned)h2 | ((unsigned)h3 << 16);
    pl.x = (unsigned)f2bf(o0 - bf2f(h0)) | ((unsigned)f2bf(o1 - bf2f(h1)) << 16);
    pl.y = (unsigned)f2bf(o2 - bf2f(h2)) | ((unsigned)f2bf(o3 - bf2f(h3)) << 16);
    int r = wid * 4 + q;
    *(uint2*)&s_hi[r * AGG_PAD + 4 * lane] = ph;
    *(uint2*)&s_lo[r * AGG_PAD + 4 * lane] = pl;
  }
  __syncthreads();

  // ---- phase 2: gemm2 tile, rows [nb, nb+16), cols [0,128), K=256 ----
  int kgrp = lane >> 4, cl = lane & 15;
  f32x4 acc[2];
  acc[0] = (f32x4){0.f, 0.f, 0.f, 0.f};
  acc[1] = (f32x4){0.f, 0.f, 0.f, 0.f};
  for (int kt = 0; kt < 8; ++kt){
    int rb = cl * AGG_PAD + kt * 32 + kgrp * 8;
    bf16x8 ah = *(const bf16x8*)&s_hi[rb];
    bf16x8 al = *(const bf16x8*)&s_lo[rb];
#pragma unroll
    for (int nn = 0; nn < 2; ++nn){
      int nt = wid * 2 + nn;
      size_t wi = ((size_t)(kt * 8 + nt) * 64 + lane) * 8;    // Nc/16 = 8
      bf16x8 bh = *(const bf16x8*)(c_W2h + wi);
      bf16x8 bl = *(const bf16x8*)(c_W2l + wi);
      acc[nn] = __builtin_amdgcn_mfma_f32_16x16x32_bf16(ah, bh, acc[nn], 0, 0, 0);
      acc[nn] = __builtin_amdgcn_mfma_f32_16x16x32_bf16(ah, bl, acc[nn], 0, 0, 0);
      acc[nn] = __builtin_amdgcn_mfma_f32_16x16x32_bf16(al, bh, acc[nn], 0, 0, 0);
    }
  }

  float asv[2], adv[2];
#pragma unroll
  for (int nn = 0; nn < 2; ++nn){
    int col = (wid * 2 + nn) * 16 + cl;
    asv[nn] = c_as2f[col]; adv[nn] = c_ad2f[col];
  }
#pragma unroll
  for (int i = 0; i < 4; ++i){
    int row = nb + kgrp * 4 + i;
    float ps = 0.f, pd = 0.f;
#pragma unroll
    for (int nn = 0; nn < 2; ++nn){
      int col = (wid * 2 + nn) * 16 + cl;
      float v = acc[nn][i];
      g_h2b[(size_t)row * C_OUT + col] = f2bf(v);
      ps += v * asv[nn]; pd += v * adv[nn];
    }
    ps += __shfl_xor(ps, 1);  pd += __shfl_xor(pd, 1);
    ps += __shfl_xor(ps, 2);  pd += __shfl_xor(pd, 2);
    ps += __shfl_xor(ps, 4);  pd += __shfl_xor(pd, 4);
    ps += __shfl_xor(ps, 8);  pd += __shfl_xor(pd, 8);
    if (cl == 0){ s_ps[wid][kgrp * 4 + i] = ps; s_pd[wid][kgrp * 4 + i] = pd; }
  }
  __syncthreads();
  if (threadIdx.x < 16){
    int r = (int)threadIdx.x;
    g_alps2[nb + r] = s_ps[0][r] + s_ps[1][r] + s_ps[2][r] + s_ps[3][r];
    g_alpd2[nb + r] = s_pd[0][r] + s_pd[1][r] + s_pd[2][r] + s_pd[3][r];
  }
}

// ---------------- layer-2 softmax + aggregation: one wave per node (R1) ----------------
__global__ __launch_bounds__(256) void agg2_k(float* OUT){
  int lane = (int)(threadIdx.x & 63);
  int n = blockIdx.x * 4 + (int)(threadIdx.x >> 6);
  int len = g_cursor[n]; if (len > CAP) len = CAP;
  int i0 = n * CAP, i1 = i0 + len;
  float adn = g_alpd2[n];
  float dpart = 0.f;
  float a0 = 0.f, a1 = 0.f;
  const unsigned int* H1 = (const unsigned int*)g_h2b;

  { // implicit self-loop
    float es = g_alps2[n] + adn;
    es = (es > 0.f) ? es : NEG_SLOPE * es;
    float wself = __expf(es);
    if (lane == 0) dpart += wself;
    unsigned int p = H1[(size_t)n * 64 + lane];
    ACC2(p, wself)
  }

  for (int base = i0; base < i1; base += 64){
    int nv = i1 - base; if (nv > 64) nv = 64;
    int sv = 0; float wv = 0.f;
    if (lane < nv){
      sv = g_srcidx[base + lane];
      float e = g_alps2[sv] + adn;
      e = (e > 0.f) ? e : NEG_SLOPE * e;
      wv = __expf(e);
    }
    dpart += wv;
    int j = 0;
    for (; j + 8 <= nv; j += 8){
      int s0 = __shfl(sv, j),     s1 = __shfl(sv, j + 1);
      int s2 = __shfl(sv, j + 2), s3 = __shfl(sv, j + 3);
      int s4 = __shfl(sv, j + 4), s5 = __shfl(sv, j + 5);
      int s6 = __shfl(sv, j + 6), s7 = __shfl(sv, j + 7);
      float w0 = __shfl(wv, j),     w1 = __shfl(wv, j + 1);
      float w2 = __shfl(wv, j + 2), w3 = __shfl(wv, j + 3);
      float w4 = __shfl(wv, j + 4), w5 = __shfl(wv, j + 5);
      float w6 = __shfl(wv, j + 6), w7 = __shfl(wv, j + 7);
      unsigned int p0 = H1[(size_t)s0 * 64 + lane];
      unsigned int p1 = H1[(size_t)s1 * 64 + lane];
      unsigned int p2 = H1[(size_t)s2 * 64 + lane];
      unsigned int p3 = H1[(size_t)s3 * 64 + lane];
      unsigned int p4 = H1[(size_t)s4 * 64 + lane];
      unsigned int p5 = H1[(size_t)s5 * 64 + lane];
      unsigned int p6 = H1[(size_t)s6 * 64 + lane];
      unsigned int p7 = H1[(size_t)s7 * 64 + lane];
      ACC2(p0, w0) ACC2(p1, w1) ACC2(p2, w2) ACC2(p3, w3)
      ACC2(p4, w4) ACC2(p5, w5) ACC2(p6, w6) ACC2(p7, w7)
    }
    for (; j + 4 <= nv; j += 4){
      int s0 = __shfl(sv, j),     s1 = __shfl(sv, j + 1);
      int s2 = __shfl(sv, j + 2), s3 = __shfl(sv, j + 3);
      float w0 = __shfl(wv, j),     w1 = __shfl(wv, j + 1);
      float w2 = __shfl(wv, j + 2), w3 = __shfl(wv, j + 3);
      unsigned int p0 = H1[(size_t)s0 * 64 + lane];
      unsigned int p1 = H1[(size_t)s1 * 64 + lane];
      unsigned int p2 = H1[(size_t)s2 * 64 + lane];
      unsigned int p3 = H1[(size_t)s3 * 64 + lane];
      ACC2(p0, w0) ACC2(p1, w1) ACC2(p2, w2) ACC2(p3, w3)
    }
    for (; j < nv; ++j){
      int s = __shfl(sv, j);
      float w = __shfl(wv, j);
      unsigned int p = H1[(size_t)s * 64 + lane];
      ACC2(p, w)
    }
  }

  float den = dpart;
#pragma unroll
  for (int o = 32; o > 0; o >>= 1) den += __shfl_xor(den, o, 64);
  float inv = 1.f / den;

  float2 o;
  o.x = a0 * inv + c_b2f[2 * lane];
  o.y = a1 * inv + c_b2f[2 * lane + 1];
  ((float2*)OUT)[(size_t)n * 64 + lane] = o;
}

extern "C" void kernel_launch(void* const* d_in, const int* in_sizes, int n_in,
                              void* d_out, int out_size, void* d_ws, size_t ws_size,
                              hipStream_t stream){
  (void)in_sizes; (void)n_in; (void)out_size; (void)d_ws; (void)ws_size;
  const void* x  = d_in[0];
  const int*  ei = (const int*)d_in[1];
  float* out = (float*)d_out;

  Ptrs ps;
  ps.p[0] = d_in[2]; ps.p[1] = d_in[3]; ps.p[2] = d_in[4]; ps.p[3] = d_in[5];
  ps.p[4] = d_in[6]; ps.p[5] = d_in[7]; ps.p[6] = d_in[8]; ps.p[7] = d_in[9];

  prep_k<<<(PREP_T + 255) / 256, 256, 0, stream>>>((const unsigned int*)x, ei, ps);

  // ---- layer 1: gemm1 + edge scatter fused (independent work, one dispatch) ----
  gemm1_k<<<GEMM1_BLKS + SCAT_BLKS, 256, 0, stream>>>(x, ei);

  // ---- agg1 + gemm2 fused (row-aligned dependency -> in-block via LDS) ----
  aggemm_k<<<N_NODES / 16, 256, 0, stream>>>();

  // ---- layer 2 aggregation ----
  agg2_k<<<N_NODES / 4, 256, 0, stream>>>(out);
}